// Round 3
// baseline (512.556 us; speedup 1.0000x reference)
//
#include <hip/hip_runtime.h>
#include <math.h>

#define C 256
#define H 64
#define W 64
#define B 32
#define HW (H*W)
#define EPS 1e-5f
#define LSTR2 256  // shorts per row of the [w][ci] LDS tiles (512 B)

typedef __attribute__((ext_vector_type(8))) short short8;   // 8 bf16
typedef __attribute__((ext_vector_type(4))) short short4v;  // 4 bf16
typedef __attribute__((ext_vector_type(4))) float f32x4;

__device__ __forceinline__ float gelu_exact(float z) {
    return 0.5f * z * (1.0f + erff(z * 0.70710678f));
}
__device__ __forceinline__ short f2bf(float f) {
    union { float f; unsigned u; } v; v.f = f;
    unsigned r = v.u + 0x7fffu + ((v.u >> 16) & 1u);
    return (short)(r >> 16);
}
__device__ __forceinline__ float bf2f(short s) {
    union { unsigned u; float f; } v; v.u = ((unsigned)(unsigned short)s) << 16;
    return v.f;
}
// XOR-swizzle (short-index units, 8-short groups) for the [w][ci] tiles.
__device__ __forceinline__ int swz8(int w) {
    return (((w & 7) ^ ((w >> 3) & 7)) << 3);
}
// XCD-aware (h,b) remap: each XCD gets 8-consecutive-h chunks (halo rows L2-hit),
// rotated across b so all XCDs get every batch (load-balanced vs expert routing).
__device__ __forceinline__ void swz_hb(int bx, int by, int& h, int& b) {
    int wg  = bx + (by << 6);
    int xcd = wg & 7, lin = wg >> 3;
    b = lin >> 3;
    int j = lin & 7;
    h = (((xcd + b) & 7) << 3) + j;
}

__global__ __launch_bounds__(256) void pool_kernel(const float* __restrict__ x,
                                                   float* __restrict__ pooled) {
    int bc = blockIdx.x;
    const float4* p4 = (const float4*)(x + (size_t)bc * HW);
    int t = threadIdx.x;
    float s = 0.f;
    for (int i = t; i < HW/4; i += 256) {
        float4 v = p4[i];
        s += v.x + v.y + v.z + v.w;
    }
    for (int off = 32; off > 0; off >>= 1) s += __shfl_down(s, off, 64);
    __shared__ float wsum[4];
    if ((t & 63) == 0) wsum[t >> 6] = s;
    __syncthreads();
    if (t == 0) pooled[bc] = (wsum[0]+wsum[1]+wsum[2]+wsum[3]) * (1.f/HW);
}

// blocks 0..191: pack 6 C*C fp32 matrices into bf16 MFMA fragments:
//   mat 0: pw0_hi  1: pw1_hi  2: pw2_hi  3: e2k_hi  4: pw2_lo  5: e2k_lo
// fragment chunk (kt,mt): lane holds M[o=mt*16+(lane&15)][ci=kt*32+(lane>>4)*8+j].
// block 192: fold BN into conv weights + sc/sh tables.
// block 193: routing (argmax logit; softmax/temp monotone, top-1 weight == 1).
__global__ __launch_bounds__(256) void prep_kernel(
    const float* __restrict__ s0, const float* __restrict__ s1,
    const float* __restrict__ s2, const float* __restrict__ s3,
    const float* __restrict__ e0k, const float* __restrict__ e1k,
    const float* __restrict__ g0, const float* __restrict__ b0,
    const float* __restrict__ m0, const float* __restrict__ v0,
    const float* __restrict__ g1, const float* __restrict__ b1,
    const float* __restrict__ m1, const float* __restrict__ v1,
    const float* __restrict__ g2, const float* __restrict__ b2,
    const float* __restrict__ m2, const float* __restrict__ v2,
    const float* __restrict__ pooled, const float* __restrict__ rw,
    const float* __restrict__ rb, int* __restrict__ idx,
    short* __restrict__ apackAll, float* __restrict__ kf0, float* __restrict__ kf1,
    float* __restrict__ scAll, float* __restrict__ shAll)
{
    if (blockIdx.x < 192) {
        int gid = blockIdx.x * 256 + threadIdx.x;       // 0..49151
        int mat = gid >> 13;                            // 0..5
        int c   = gid & 8191;
        int lane = c & 63;
        int ktmt = c >> 6;
        int mt = ktmt & 15, kt = ktmt >> 4;
        int o  = mt*16 + (lane & 15);
        int ci = kt*32 + (lane >> 4)*8;
        const float* src = (mat == 0) ? s0 : (mat == 1) ? s1 :
                           (mat == 2 || mat == 4) ? s2 : s3;
        bool lo = (mat >= 4);
        const float* p = src + o*C + ci;
        short8 v;
#pragma unroll
        for (int j = 0; j < 8; ++j) {
            float f = p[j];
            short hj = f2bf(f);
            v[j] = lo ? f2bf(f - bf2f(hj)) : hj;
        }
        *(short8*)&apackAll[(size_t)gid * 8] = v;
    } else if (blockIdx.x == 192) {
        int t = threadIdx.x;   // = ci
        {
            float s = g0[t] / sqrtf(v0[t] + EPS);
            scAll[t] = s; shAll[t] = b0[t] - m0[t]*s;
#pragma unroll
            for (int j = 0; j < 9; ++j) kf0[t*12+j] = e0k[t*9+j]*s;
            kf0[t*12+9] = 0.f; kf0[t*12+10] = 0.f; kf0[t*12+11] = 0.f;
        }
        {
            float s = g1[t] / sqrtf(v1[t] + EPS);
            scAll[C+t] = s; shAll[C+t] = b1[t] - m1[t]*s;
#pragma unroll
            for (int j = 0; j < 9; ++j) kf1[t*12+j] = e1k[t*9+j]*s;
            kf1[t*12+9] = 0.f; kf1[t*12+10] = 0.f; kf1[t*12+11] = 0.f;
        }
        {
            float s = g2[t] / sqrtf(v2[t] + EPS);
            scAll[2*C+t] = s; shAll[2*C+t] = b2[t] - m2[t]*s;
        }
    } else {
        int t = threadIdx.x;
        if (t < 192) {
            int e = t >> 6, lane = t & 63;
            __shared__ float lg[3*B];
            for (int b = 0; b < B; ++b) {
                const float* p = pooled + b*C;
                const float* w = rw + e*C;
                float s = 0.f;
#pragma unroll
                for (int i = 0; i < 4; ++i) s += p[lane + i*64] * w[lane + i*64];
                for (int off = 32; off > 0; off >>= 1) s += __shfl_down(s, off, 64);
                if (lane == 0) lg[b*3 + e] = s + rb[e];
            }
            __syncthreads();
            if (t < B) {
                float l0 = lg[t*3], l1 = lg[t*3+1], l2 = lg[t*3+2];
                int best = 0; float bv = l0;
                if (l1 > bv) { bv = l1; best = 1; }
                if (l2 > bv) { bv = l2; best = 2; }
                idx[t] = best;
            }
        } else {
            __syncthreads();   // keep barrier uniform across the block
        }
    }
}

// conv for dilation DIL; writes gelu(BN(conv)) bf16 TRANSPOSED into lds[w][ci^swz]
template<int DIL>
__device__ __forceinline__ void conv_rows_t(const float* __restrict__ x,
                                            const float* __restrict__ kf,
                                            const float* __restrict__ sh,
                                            short* __restrict__ lds,
                                            int b, int h, int t) {
    const int strip = t & 7;
    const int w0 = strip * 8;
    const int cib = t >> 3;
#pragma unroll 1
    for (int iter = 0; iter < 8; ++iter) {
        int ci = iter*32 + cib;
        const float* xpl = x + (size_t)(b*C + ci) * HW;
        float fr[3][16];
        bool rv[3];
#pragma unroll
        for (int ky = 0; ky < 3; ++ky) {
            int y = h + (ky - 1)*DIL;
            rv[ky] = ((unsigned)y < H);      // wave-uniform
            if (rv[ky]) {
                const float* row = xpl + y*W;
                float4 fa = (strip > 0) ? *(const float4*)(row + w0 - 4) : float4{0,0,0,0};
                float4 fb = *(const float4*)(row + w0);
                float4 fc = *(const float4*)(row + w0 + 4);
                float4 fd = (strip < 7) ? *(const float4*)(row + w0 + 8) : float4{0,0,0,0};
                fr[ky][0]=fa.x; fr[ky][1]=fa.y; fr[ky][2]=fa.z; fr[ky][3]=fa.w;
                fr[ky][4]=fb.x; fr[ky][5]=fb.y; fr[ky][6]=fb.z; fr[ky][7]=fb.w;
                fr[ky][8]=fc.x; fr[ky][9]=fc.y; fr[ky][10]=fc.z; fr[ky][11]=fc.w;
                fr[ky][12]=fd.x; fr[ky][13]=fd.y; fr[ky][14]=fd.z; fr[ky][15]=fd.w;
            }
        }
        float4 k0 = *(const float4*)(kf + ci*12);
        float4 k1v = *(const float4*)(kf + ci*12 + 4);
        float wk[9] = {k0.x,k0.y,k0.z,k0.w,k1v.x,k1v.y,k1v.z,k1v.w, kf[ci*12+8]};
        float acc8[8] = {0,0,0,0,0,0,0,0};
#pragma unroll
        for (int ky = 0; ky < 3; ++ky) {
            if (rv[ky]) {
#pragma unroll
                for (int kx = 0; kx < 3; ++kx) {
                    float wv = wk[ky*3+kx];
                    const int base = 4 + (kx - 1)*DIL;   // compile-time
#pragma unroll
                    for (int j = 0; j < 8; ++j) acc8[j] += wv * fr[ky][base + j];
                }
            }
        }
        float shv = sh[ci];
#pragma unroll
        for (int j = 0; j < 8; ++j) {
            int w = w0 + j;
            lds[w*LSTR2 + (ci ^ swz8(w))] = f2bf(gelu_exact(acc8[j] + shv));
        }
    }
}

// 3-product split-bf16 GEMM over [w][ci] hi/lo LDS tiles (NWT w-subtiles of 16):
// acc += Ahi*Bhi + Ahi*Blo + Alo*Bhi  (~fp32 accurate; lo*lo term ~2^-18 dropped)
template<int NWT>
__device__ __forceinline__ void gemm3t(const short* __restrict__ aH,
                                       const short* __restrict__ aL,
                                       const short* __restrict__ ldsH,
                                       const short* __restrict__ ldsL,
                                       int lane, int wid, f32x4 acc[4][NWT])
{
    const int l15 = lane & 15, quad = lane >> 4;
    for (int kt = 0; kt < 8; ++kt) {
        short8 bH[NWT], bL[NWT];
#pragma unroll
        for (int wt = 0; wt < NWT; ++wt) {
            int w = wt*16 + l15;
            int off = w*LSTR2 + ((kt*32 + quad*8) ^ swz8(w));
            bH[wt] = *(const short8*)&ldsH[off];
            bL[wt] = *(const short8*)&ldsL[off];
        }
        short8 fH[4], fL[4];
#pragma unroll
        for (int i = 0; i < 4; ++i) {
            size_t off = ((size_t)(kt*16 + wid*4 + i)*64 + lane)*8;
            fH[i] = *(const short8*)&aH[off];
            fL[i] = *(const short8*)&aL[off];
        }
#pragma unroll
        for (int i = 0; i < 4; ++i)
#pragma unroll
            for (int wt = 0; wt < NWT; ++wt) {
                acc[i][wt] = __builtin_amdgcn_mfma_f32_16x16x32_bf16(fH[i], bH[wt], acc[i][wt], 0, 0, 0);
                acc[i][wt] = __builtin_amdgcn_mfma_f32_16x16x32_bf16(fH[i], bL[wt], acc[i][wt], 0, 0, 0);
                acc[i][wt] = __builtin_amdgcn_mfma_f32_16x16x32_bf16(fL[i], bH[wt], acc[i][wt], 0, 0, 0);
            }
    }
}

// Merged expert kernel, one block per (h,b) — EVERY block does work.
// e<2: dwconv+BN+gelu -> feat[w64][ci] (32 KB) -> pw GEMM -> out.
// e==2: two 32-pixel half-tiles, each: x hi/lo (16+16 KB) -> e2k GEMM (3-prod)
//       -> BN+gelu -> feat hi/lo (overwrite) -> pw2 GEMM (3-prod) -> out.
// Peak LDS 32 KB for BOTH paths -> 5 blocks/CU.
__global__ __launch_bounds__(256) void kexp(
    const float* __restrict__ x, const int* __restrict__ idx,
    const float* __restrict__ kf0, const float* __restrict__ kf1,
    const float* __restrict__ scAll, const float* __restrict__ shAll,
    const short* __restrict__ apackAll,
    const float* __restrict__ e0pb, const float* __restrict__ e1pb,
    const float* __restrict__ e2pb,
    float* __restrict__ out)
{
    __shared__ short lds[W*LSTR2];   // 32 KB
    int h, b;
    swz_hb(blockIdx.x, blockIdx.y, h, b);
    const int e = idx[b];
    const int t = threadIdx.x;
    const int lane = t & 63, wid = t >> 6;
    const int l15 = lane & 15, quad = lane >> 4;

    if (e < 2) {
        if (e == 0) conv_rows_t<1>(x, kf0, shAll,     lds, b, h, t);
        else        conv_rows_t<2>(x, kf1, shAll + C, lds, b, h, t);
        __syncthreads();

        // GEMM2: D[o][w] = pw . feat ; wave wid owns o = wid*64..+63
        const short* pwf = apackAll + (size_t)e * 65536;
        f32x4 acc[4][4];
#pragma unroll
        for (int i = 0; i < 4; ++i)
#pragma unroll
            for (int wt = 0; wt < 4; ++wt) acc[i][wt] = (f32x4){0.f,0.f,0.f,0.f};
        for (int kt = 0; kt < 8; ++kt) {
            short8 bf[4];
#pragma unroll
            for (int wt = 0; wt < 4; ++wt) {
                int w = wt*16 + l15;
                bf[wt] = *(const short8*)&lds[w*LSTR2 + ((kt*32 + quad*8) ^ swz8(w))];
            }
            short8 af[4];
#pragma unroll
            for (int i = 0; i < 4; ++i)
                af[i] = *(const short8*)&pwf[((size_t)(kt*16 + wid*4 + i)*64 + lane)*8];
#pragma unroll
            for (int i = 0; i < 4; ++i)
#pragma unroll
                for (int wt = 0; wt < 4; ++wt)
                    acc[i][wt] = __builtin_amdgcn_mfma_f32_16x16x32_bf16(
                        af[i], bf[wt], acc[i][wt], 0, 0, 0);
        }

        const float* pb = (e == 0) ? e0pb : e1pb;
#pragma unroll
        for (int i = 0; i < 4; ++i) {
            int ob = wid*64 + i*16 + quad*4;
            float4 p4 = *(const float4*)&pb[ob];
            float pbv[4] = {p4.x, p4.y, p4.z, p4.w};
#pragma unroll
            for (int wt = 0; wt < 4; ++wt) {
                int w = wt*16 + l15;
#pragma unroll
                for (int r = 0; r < 4; ++r)
                    out[((size_t)(b*C + ob + r))*HW + h*W + w] = acc[i][wt][r] + pbv[r];
            }
        }
    } else {
        short* ldsH = lds;           // 8192 shorts (16 KB), [w32][ci^swz]
        short* ldsL = lds + 32*LSTR2;
        const float* sc2 = scAll + 2*C;
        const float* sh2 = shAll + 2*C;
#pragma unroll 1
        for (int hf = 0; hf < 2; ++hf) {
            if (hf) __syncthreads();   // previous half's GEMM2 reads done
            // stage x half: lanes cover 32 consecutive w (coalesced 128B x2/instr)
            {
                const int wl = t & 31, g = t >> 5;     // g in 0..7
                const int vsw = swz8(wl);
#pragma unroll
                for (int k = 0; k < 4; ++k) {
                    int ci0 = g*32 + k*8;
                    const float* px = x + ((size_t)(b*C + ci0)*H + h)*W + hf*32 + wl;
                    float f[8];
#pragma unroll
                    for (int j = 0; j < 8; ++j) f[j] = px[(size_t)j * HW];
                    short8 hi, lo;
#pragma unroll
                    for (int j = 0; j < 8; ++j) {
                        short hj = f2bf(f[j]);
                        hi[j] = hj;
                        lo[j] = f2bf(f[j] - bf2f(hj));
                    }
                    int col = ci0 ^ vsw;
                    *(short8*)&ldsH[wl*LSTR2 + col] = hi;
                    *(short8*)&ldsL[wl*LSTR2 + col] = lo;
                }
            }
            __syncthreads();

            // GEMM1: z[co][w32] = e2k @ x  (split-accurate)
            f32x4 acc[4][2];
#pragma unroll
            for (int i = 0; i < 4; ++i)
#pragma unroll
                for (int wt = 0; wt < 2; ++wt) acc[i][wt] = (f32x4){0.f,0.f,0.f,0.f};
            gemm3t<2>(apackAll + (size_t)3*65536, apackAll + (size_t)5*65536,
                      ldsH, ldsL, lane, wid, acc);
            __syncthreads();   // all waves done reading x before feat overwrites

            // BN + gelu; split feat hi/lo, store [w32][co]
#pragma unroll
            for (int i = 0; i < 4; ++i) {
                int cob = wid*64 + i*16 + quad*4;
                float4 s4 = *(const float4*)&sc2[cob];
                float4 h4 = *(const float4*)&sh2[cob];
                float ss[4] = {s4.x, s4.y, s4.z, s4.w};
                float hh[4] = {h4.x, h4.y, h4.z, h4.w};
#pragma unroll
                for (int wt = 0; wt < 2; ++wt) {
                    int w = wt*16 + l15;
                    int col = cob ^ swz8(w);   // low 2 bits of cob untouched by swz
                    short4v ph, pl;
#pragma unroll
                    for (int r = 0; r < 4; ++r) {
                        float f = gelu_exact(acc[i][wt][r]*ss[r] + hh[r]);
                        short hj = f2bf(f);
                        ph[r] = hj;
                        pl[r] = f2bf(f - bf2f(hj));
                    }
                    *(short4v*)&ldsH[w*LSTR2 + col] = ph;
                    *(short4v*)&ldsL[w*LSTR2 + col] = pl;
                }
            }
            __syncthreads();

            // GEMM2: out[o][w32] = pw2 @ feat  (split-accurate)
#pragma unroll
            for (int i = 0; i < 4; ++i)
#pragma unroll
                for (int wt = 0; wt < 2; ++wt) acc[i][wt] = (f32x4){0.f,0.f,0.f,0.f};
            gemm3t<2>(apackAll + (size_t)2*65536, apackAll + (size_t)4*65536,
                      ldsH, ldsL, lane, wid, acc);

            // epilogue: + pb, store fp32
#pragma unroll
            for (int i = 0; i < 4; ++i) {
                int ob = wid*64 + i*16 + quad*4;
                float4 p4 = *(const float4*)&e2pb[ob];
                float pbv[4] = {p4.x, p4.y, p4.z, p4.w};
#pragma unroll
                for (int wt = 0; wt < 2; ++wt) {
                    int w = hf*32 + wt*16 + l15;
#pragma unroll
                    for (int r = 0; r < 4; ++r)
                        out[((size_t)(b*C + ob + r))*HW + h*W + w] = acc[i][wt][r] + pbv[r];
                }
            }
        }
    }
}

extern "C" void kernel_launch(void* const* d_in, const int* in_sizes, int n_in,
                              void* d_out, int out_size, void* d_ws, size_t ws_size,
                              hipStream_t stream) {
    const float* x    = (const float*)d_in[0];
    const float* rw   = (const float*)d_in[1];
    const float* rb   = (const float*)d_in[2];
    const float* e0k  = (const float*)d_in[3];
    const float* e0g  = (const float*)d_in[4];
    const float* e0b  = (const float*)d_in[5];
    const float* e0m  = (const float*)d_in[6];
    const float* e0v  = (const float*)d_in[7];
    const float* e0pw = (const float*)d_in[8];
    const float* e0pb = (const float*)d_in[9];
    const float* e1k  = (const float*)d_in[10];
    const float* e1g  = (const float*)d_in[11];
    const float* e1b  = (const float*)d_in[12];
    const float* e1m  = (const float*)d_in[13];
    const float* e1v  = (const float*)d_in[14];
    const float* e1pw = (const float*)d_in[15];
    const float* e1pb = (const float*)d_in[16];
    const float* e2k  = (const float*)d_in[17];
    const float* e2g  = (const float*)d_in[18];
    const float* e2b  = (const float*)d_in[19];
    const float* e2m  = (const float*)d_in[20];
    const float* e2v  = (const float*)d_in[21];
    const float* e2pw = (const float*)d_in[22];
    const float* e2pb = (const float*)d_in[23];
    float* out = (float*)d_out;

    char* wsb = (char*)d_ws;
    float* pooled   = (float*)wsb;                       // 32768 B
    int*   idx      = (int*)(wsb + 32768);               // 128 B
    float* scAll    = (float*)(wsb + 32896);             // 3072 B
    float* shAll    = (float*)(wsb + 35968);             // 3072 B
    float* kf0      = (float*)(wsb + 39040);             // 12288 B
    float* kf1      = (float*)(wsb + 51328);             // 12288 B
    short* apackAll = (short*)(wsb + 63616);             // 786432 B (6 mats)

    pool_kernel<<<B*C, 256, 0, stream>>>(x, pooled);
    prep_kernel<<<194, 256, 0, stream>>>(e0pw, e1pw, e2pw, e2k, e0k, e1k,
                                         e0g, e0b, e0m, e0v,
                                         e1g, e1b, e1m, e1v,
                                         e2g, e2b, e2m, e2v,
                                         pooled, rw, rb, idx,
                                         apackAll, kf0, kf1, scAll, shAll);
    kexp<<<dim3(H, B), 256, 0, stream>>>(x, idx, kf0, kf1, scAll, shAll,
                                         apackAll, e0pb, e1pb, e2pb, out);
}

// Round 5
// 385.795 us; speedup vs baseline: 1.3286x; 1.3286x over previous
//
#include <hip/hip_runtime.h>
#include <math.h>

#define C 256
#define H 64
#define W 64
#define B 32
#define HW (H*W)
#define EPS 1e-5f
#define LSTR2 256  // shorts per row of the [w][ci] LDS tiles (512 B)

typedef __attribute__((ext_vector_type(8))) short short8;   // 8 bf16
typedef __attribute__((ext_vector_type(4))) short short4v;  // 4 bf16
typedef __attribute__((ext_vector_type(4))) float f32x4;

// Branchless gelu, exact-mode accurate: Abramowitz-Stegun 7.1.26 erf
// (max abs err 1.5e-7 -> gelu abs err <= ~1e-6, far under bf16 rounding).
// gelu(z) = max(z,0) - 0.5*|z|*poly(t)*exp(-z^2/2),  t = 1/(1+0.3275911*|z|/sqrt2)
__device__ __forceinline__ float gelu_fast(float z) {
    float a = fabsf(z) * 0.70710678f;
    float t = __frcp_rn(1.f + 0.3275911f * a);
    float p = t * (0.254829592f + t * (-0.284496736f + t * (1.421413741f +
              t * (-1.453152027f + t * 1.061405429f))));
    float e = __expf(-a * a);
    float q = 0.5f * fabsf(z) * p * e;
    return fmaxf(z, 0.f) - q;
}
__device__ __forceinline__ short f2bf(float f) {
    union { float f; unsigned u; } v; v.f = f;
    unsigned r = v.u + 0x7fffu + ((v.u >> 16) & 1u);
    return (short)(r >> 16);
}
__device__ __forceinline__ float bf2f(short s) {
    union { unsigned u; float f; } v; v.u = ((unsigned)(unsigned short)s) << 16;
    return v.f;
}
// XOR-swizzle (short-index units, 8-short groups) for the [w][ci] tiles.
__device__ __forceinline__ int swz8(int w) {
    return (((w & 7) ^ ((w >> 3) & 7)) << 3);
}
// XCD-aware (h,b) remap: each XCD gets 8-consecutive-h chunks (halo rows L2-hit),
// rotated across b so all XCDs get every batch (load-balanced vs expert routing).
__device__ __forceinline__ void swz_hb(int bx, int by, int& h, int& b) {
    int wg  = bx + (by << 6);
    int xcd = wg & 7, lin = wg >> 3;
    b = lin >> 3;
    int j = lin & 7;
    h = (((xcd + b) & 7) << 3) + j;
}

__global__ __launch_bounds__(256) void pool_kernel(const float* __restrict__ x,
                                                   float* __restrict__ pooled) {
    int bc = blockIdx.x;
    const float4* p4 = (const float4*)(x + (size_t)bc * HW);
    int t = threadIdx.x;
    float s = 0.f;
    for (int i = t; i < HW/4; i += 256) {
        float4 v = p4[i];
        s += v.x + v.y + v.z + v.w;
    }
    for (int off = 32; off > 0; off >>= 1) s += __shfl_down(s, off, 64);
    __shared__ float wsum[4];
    if ((t & 63) == 0) wsum[t >> 6] = s;
    __syncthreads();
    if (t == 0) pooled[bc] = (wsum[0]+wsum[1]+wsum[2]+wsum[3]) * (1.f/HW);
}

// blocks 0..191: pack 6 C*C fp32 matrices into bf16 MFMA fragments:
//   mat 0: pw0_hi  1: pw1_hi  2: pw2_hi  3: e2k_hi  4: pw2_lo  5: e2k_lo
// fragment chunk (kt,mt): lane holds M[o=mt*16+(lane&15)][ci=kt*32+(lane>>4)*8+j].
// block 192: fold BN into conv weights + sc/sh tables.
// block 193: routing (argmax logit; softmax/temp monotone, top-1 weight == 1).
__global__ __launch_bounds__(256) void prep_kernel(
    const float* __restrict__ s0, const float* __restrict__ s1,
    const float* __restrict__ s2, const float* __restrict__ s3,
    const float* __restrict__ e0k, const float* __restrict__ e1k,
    const float* __restrict__ g0, const float* __restrict__ b0,
    const float* __restrict__ m0, const float* __restrict__ v0,
    const float* __restrict__ g1, const float* __restrict__ b1,
    const float* __restrict__ m1, const float* __restrict__ v1,
    const float* __restrict__ g2, const float* __restrict__ b2,
    const float* __restrict__ m2, const float* __restrict__ v2,
    const float* __restrict__ pooled, const float* __restrict__ rw,
    const float* __restrict__ rb, int* __restrict__ idx,
    short* __restrict__ apackAll, float* __restrict__ kf0, float* __restrict__ kf1,
    float* __restrict__ scAll, float* __restrict__ shAll)
{
    if (blockIdx.x < 192) {
        int gid = blockIdx.x * 256 + threadIdx.x;       // 0..49151
        int mat = gid >> 13;                            // 0..5
        int c   = gid & 8191;
        int lane = c & 63;
        int ktmt = c >> 6;
        int mt = ktmt & 15, kt = ktmt >> 4;
        int o  = mt*16 + (lane & 15);
        int ci = kt*32 + (lane >> 4)*8;
        const float* src = (mat == 0) ? s0 : (mat == 1) ? s1 :
                           (mat == 2 || mat == 4) ? s2 : s3;
        bool lo = (mat >= 4);
        const float* p = src + o*C + ci;
        short8 v;
#pragma unroll
        for (int j = 0; j < 8; ++j) {
            float f = p[j];
            short hj = f2bf(f);
            v[j] = lo ? f2bf(f - bf2f(hj)) : hj;
        }
        *(short8*)&apackAll[(size_t)gid * 8] = v;
    } else if (blockIdx.x == 192) {
        int t = threadIdx.x;   // = ci
        {
            float s = g0[t] / sqrtf(v0[t] + EPS);
            scAll[t] = s; shAll[t] = b0[t] - m0[t]*s;
#pragma unroll
            for (int j = 0; j < 9; ++j) kf0[t*12+j] = e0k[t*9+j]*s;
            kf0[t*12+9] = 0.f; kf0[t*12+10] = 0.f; kf0[t*12+11] = 0.f;
        }
        {
            float s = g1[t] / sqrtf(v1[t] + EPS);
            scAll[C+t] = s; shAll[C+t] = b1[t] - m1[t]*s;
#pragma unroll
            for (int j = 0; j < 9; ++j) kf1[t*12+j] = e1k[t*9+j]*s;
            kf1[t*12+9] = 0.f; kf1[t*12+10] = 0.f; kf1[t*12+11] = 0.f;
        }
        {
            float s = g2[t] / sqrtf(v2[t] + EPS);
            scAll[2*C+t] = s; shAll[2*C+t] = b2[t] - m2[t]*s;
        }
    } else {
        // routing block — single UNIFORM barrier (no divergent __syncthreads)
        __shared__ float lg[3*B];
        int t = threadIdx.x;
        int e = t >> 6, lane = t & 63;
        if (e < 3) {
            for (int b = 0; b < B; ++b) {
                const float* p = pooled + b*C;
                const float* w = rw + e*C;
                float s = 0.f;
#pragma unroll
                for (int i = 0; i < 4; ++i) s += p[lane + i*64] * w[lane + i*64];
                for (int off = 32; off > 0; off >>= 1) s += __shfl_down(s, off, 64);
                if (lane == 0) lg[b*3 + e] = s + rb[e];
            }
        }
        __syncthreads();
        if (t < B) {
            float l0 = lg[t*3], l1 = lg[t*3+1], l2 = lg[t*3+2];
            int best = 0; float bv = l0;
            if (l1 > bv) { bv = l1; best = 1; }
            if (l2 > bv) { bv = l2; best = 2; }
            idx[t] = best;
        }
    }
}

// conv for dilation DIL; writes gelu(BN(conv)) bf16 TRANSPOSED into lds[w][ci^swz]
template<int DIL>
__device__ __forceinline__ void conv_rows_t(const float* __restrict__ x,
                                            const float* __restrict__ kf,
                                            const float* __restrict__ sh,
                                            short* __restrict__ lds,
                                            int b, int h, int t) {
    const int strip = t & 7;
    const int w0 = strip * 8;
    const int cib = t >> 3;
#pragma unroll 1
    for (int iter = 0; iter < 8; ++iter) {
        int ci = iter*32 + cib;
        const float* xpl = x + (size_t)(b*C + ci) * HW;
        float fr[3][16];
        bool rv[3];
#pragma unroll
        for (int ky = 0; ky < 3; ++ky) {
            int y = h + (ky - 1)*DIL;
            rv[ky] = ((unsigned)y < H);      // wave-uniform
            if (rv[ky]) {
                const float* row = xpl + y*W;
                float4 fa = (strip > 0) ? *(const float4*)(row + w0 - 4) : float4{0,0,0,0};
                float4 fb = *(const float4*)(row + w0);
                float4 fc = *(const float4*)(row + w0 + 4);
                float4 fd = (strip < 7) ? *(const float4*)(row + w0 + 8) : float4{0,0,0,0};
                fr[ky][0]=fa.x; fr[ky][1]=fa.y; fr[ky][2]=fa.z; fr[ky][3]=fa.w;
                fr[ky][4]=fb.x; fr[ky][5]=fb.y; fr[ky][6]=fb.z; fr[ky][7]=fb.w;
                fr[ky][8]=fc.x; fr[ky][9]=fc.y; fr[ky][10]=fc.z; fr[ky][11]=fc.w;
                fr[ky][12]=fd.x; fr[ky][13]=fd.y; fr[ky][14]=fd.z; fr[ky][15]=fd.w;
            }
        }
        float4 k0 = *(const float4*)(kf + ci*12);
        float4 k1v = *(const float4*)(kf + ci*12 + 4);
        float wk[9] = {k0.x,k0.y,k0.z,k0.w,k1v.x,k1v.y,k1v.z,k1v.w, kf[ci*12+8]};
        float acc8[8] = {0,0,0,0,0,0,0,0};
#pragma unroll
        for (int ky = 0; ky < 3; ++ky) {
            if (rv[ky]) {
#pragma unroll
                for (int kx = 0; kx < 3; ++kx) {
                    float wv = wk[ky*3+kx];
                    const int base = 4 + (kx - 1)*DIL;   // compile-time
#pragma unroll
                    for (int j = 0; j < 8; ++j) acc8[j] += wv * fr[ky][base + j];
                }
            }
        }
        float shv = sh[ci];
#pragma unroll
        for (int j = 0; j < 8; ++j) {
            int w = w0 + j;
            lds[w*LSTR2 + (ci ^ swz8(w))] = f2bf(gelu_fast(acc8[j] + shv));
        }
    }
}

// Conv experts, fully fused per (h,b): dwconv+BN+gelu -> feat[w][ci] in LDS ->
// GEMM2 (pw_hi frags from global, feat B-frags via ds_read_b128) -> +pb -> out.
__global__ __launch_bounds__(256) void kconv(
    const float* __restrict__ x, const int* __restrict__ idx,
    const float* __restrict__ kf0, const float* __restrict__ kf1,
    const float* __restrict__ shAll, const short* __restrict__ apackAll,
    const float* __restrict__ e0pb, const float* __restrict__ e1pb,
    float* __restrict__ out)
{
    __shared__ short lds[W*LSTR2];   // 32 KB, [w][ci^swz]
    int h, b;
    swz_hb(blockIdx.x, blockIdx.y, h, b);
    const int e = idx[b];
    if (e >= 2) return;
    const int t = threadIdx.x;
    const int lane = t & 63, wid = t >> 6;
    const int l15 = lane & 15, quad = lane >> 4;

    if (e == 0) conv_rows_t<1>(x, kf0, shAll,     lds, b, h, t);
    else        conv_rows_t<2>(x, kf1, shAll + C, lds, b, h, t);
    __syncthreads();

    // GEMM2: D[o][w] = pw . feat ; wave wid owns o = wid*64..+63
    const short* pwf = apackAll + (size_t)e * 65536;
    f32x4 acc[4][4];
#pragma unroll
    for (int i = 0; i < 4; ++i)
#pragma unroll
        for (int wt = 0; wt < 4; ++wt) acc[i][wt] = (f32x4){0.f,0.f,0.f,0.f};
    for (int kt = 0; kt < 8; ++kt) {
        short8 bf[4];
#pragma unroll
        for (int wt = 0; wt < 4; ++wt) {
            int w = wt*16 + l15;
            bf[wt] = *(const short8*)&lds[w*LSTR2 + ((kt*32 + quad*8) ^ swz8(w))];
        }
        short8 af[4];
#pragma unroll
        for (int i = 0; i < 4; ++i)
            af[i] = *(const short8*)&pwf[((size_t)(kt*16 + wid*4 + i)*64 + lane)*8];
#pragma unroll
        for (int i = 0; i < 4; ++i)
#pragma unroll
            for (int wt = 0; wt < 4; ++wt)
                acc[i][wt] = __builtin_amdgcn_mfma_f32_16x16x32_bf16(
                    af[i], bf[wt], acc[i][wt], 0, 0, 0);
    }

    const float* pb = (e == 0) ? e0pb : e1pb;
#pragma unroll
    for (int i = 0; i < 4; ++i) {
        int ob = wid*64 + i*16 + quad*4;
        float4 p4 = *(const float4*)&pb[ob];
        float pbv[4] = {p4.x, p4.y, p4.z, p4.w};
#pragma unroll
        for (int wt = 0; wt < 4; ++wt) {
            int w = wt*16 + l15;
#pragma unroll
            for (int r = 0; r < 4; ++r)
                out[((size_t)(b*C + ob + r))*HW + h*W + w] = acc[i][wt][r] + pbv[r];
        }
    }
}

// 3-product split-bf16 GEMM over [w][ci] hi/lo LDS tiles (ds_read_b128 B-frags):
// acc += Ahi*Bhi + Ahi*Blo + Alo*Bhi  (~fp32 accurate; lo*lo term ~2^-18 dropped)
__device__ __forceinline__ void gemm3t(const short* __restrict__ aH,
                                       const short* __restrict__ aL,
                                       const short* __restrict__ ldsH,
                                       const short* __restrict__ ldsL,
                                       int lane, int wid, f32x4 acc[4][4])
{
    const int l15 = lane & 15, quad = lane >> 4;
    for (int kt = 0; kt < 8; ++kt) {
        short8 bH[4], bL[4];
#pragma unroll
        for (int wt = 0; wt < 4; ++wt) {
            int w = wt*16 + l15;
            int off = w*LSTR2 + ((kt*32 + quad*8) ^ swz8(w));
            bH[wt] = *(const short8*)&ldsH[off];
            bL[wt] = *(const short8*)&ldsL[off];
        }
        short8 fH[4], fL[4];
#pragma unroll
        for (int i = 0; i < 4; ++i) {
            size_t off = ((size_t)(kt*16 + wid*4 + i)*64 + lane)*8;
            fH[i] = *(const short8*)&aH[off];
            fL[i] = *(const short8*)&aL[off];
        }
#pragma unroll
        for (int i = 0; i < 4; ++i)
#pragma unroll
            for (int wt = 0; wt < 4; ++wt) {
                acc[i][wt] = __builtin_amdgcn_mfma_f32_16x16x32_bf16(fH[i], bH[wt], acc[i][wt], 0, 0, 0);
                acc[i][wt] = __builtin_amdgcn_mfma_f32_16x16x32_bf16(fH[i], bL[wt], acc[i][wt], 0, 0, 0);
                acc[i][wt] = __builtin_amdgcn_mfma_f32_16x16x32_bf16(fL[i], bH[wt], acc[i][wt], 0, 0, 0);
            }
    }
}

// e2 expert, fused full path per (h,b): x hi/lo [w][ci] tiles -> e2k GEMM (3-prod)
// -> BN+gelu -> feat hi/lo tiles -> pw2 GEMM (3-prod) -> +pb -> out (fp32).
__global__ __launch_bounds__(256) void ke2(
    const float* __restrict__ x, const int* __restrict__ idx,
    const float* __restrict__ scAll, const float* __restrict__ shAll,
    const short* __restrict__ apackAll, const float* __restrict__ e2pb,
    float* __restrict__ out)
{
    __shared__ short ldsH[W*LSTR2];   // 32 KB hi tile [w][ci^swz]
    __shared__ short ldsL[W*LSTR2];   // 32 KB lo tile
    int h, b;
    swz_hb(blockIdx.x, blockIdx.y, h, b);
    if (idx[b] != 2) return;
    const int t = threadIdx.x;
    const int lane = t & 63, wid = t >> 6;
    const int l15 = lane & 15, quad = lane >> 4;

    // stage x row h: channel-direction loads (lane = w -> 256B/inst coalesced),
    // 16B LDS row writes
    {
        const int w = t & 63;
        const int vsw = swz8(w);
        const int ci0w = wid * 64;
#pragma unroll 1
        for (int k = 0; k < 8; ++k) {
            int ci0 = ci0w + k*8;
            const float* px = x + ((size_t)(b*C + ci0)*H + h)*W + w;
            float f[8];
#pragma unroll
            for (int j = 0; j < 8; ++j) f[j] = px[(size_t)j * HW];
            short8 hi, lo;
#pragma unroll
            for (int j = 0; j < 8; ++j) {
                short hj = f2bf(f[j]);
                hi[j] = hj;
                lo[j] = f2bf(f[j] - bf2f(hj));
            }
            int col = ci0 ^ vsw;
            *(short8*)&ldsH[w*LSTR2 + col] = hi;
            *(short8*)&ldsL[w*LSTR2 + col] = lo;
        }
    }
    __syncthreads();

    // GEMM1: z[co][w] = e2k @ x  (split-accurate)
    f32x4 acc[4][4];
#pragma unroll
    for (int i = 0; i < 4; ++i)
#pragma unroll
        for (int wt = 0; wt < 4; ++wt) acc[i][wt] = (f32x4){0.f,0.f,0.f,0.f};
    gemm3t(apackAll + (size_t)3*65536, apackAll + (size_t)5*65536,
           ldsH, ldsL, lane, wid, acc);
    __syncthreads();   // all waves done reading x before feat overwrites tiles

    // BN + gelu; split feat hi/lo, store [w][co^swz]
    {
        const float* sc2 = scAll + 2*C;
        const float* sh2 = shAll + 2*C;
#pragma unroll
        for (int i = 0; i < 4; ++i) {
            int cob = wid*64 + i*16 + quad*4;
            float4 s4 = *(const float4*)&sc2[cob];
            float4 h4 = *(const float4*)&sh2[cob];
            float ss[4] = {s4.x, s4.y, s4.z, s4.w};
            float hh[4] = {h4.x, h4.y, h4.z, h4.w};
#pragma unroll
            for (int wt = 0; wt < 4; ++wt) {
                int w = wt*16 + l15;
                int col = cob ^ swz8(w);   // swz flips bits>=3: 4-short groups kept
                short4v ph, pl;
#pragma unroll
                for (int r = 0; r < 4; ++r) {
                    float f = gelu_fast(acc[i][wt][r]*ss[r] + hh[r]);
                    short hj = f2bf(f);
                    ph[r] = hj;
                    pl[r] = f2bf(f - bf2f(hj));
                }
                *(short4v*)&ldsH[w*LSTR2 + col] = ph;
                *(short4v*)&ldsL[w*LSTR2 + col] = pl;
            }
        }
    }
    __syncthreads();

    // GEMM2: out[o][w] = pw2 @ feat  (split-accurate)
#pragma unroll
    for (int i = 0; i < 4; ++i)
#pragma unroll
        for (int wt = 0; wt < 4; ++wt) acc[i][wt] = (f32x4){0.f,0.f,0.f,0.f};
    gemm3t(apackAll + (size_t)2*65536, apackAll + (size_t)4*65536,
           ldsH, ldsL, lane, wid, acc);

    // epilogue: + pb, store fp32
#pragma unroll
    for (int i = 0; i < 4; ++i) {
        int ob = wid*64 + i*16 + quad*4;
        float4 p4 = *(const float4*)&e2pb[ob];
        float pbv[4] = {p4.x, p4.y, p4.z, p4.w};
#pragma unroll
        for (int wt = 0; wt < 4; ++wt) {
            int w = wt*16 + l15;
#pragma unroll
            for (int r = 0; r < 4; ++r)
                out[((size_t)(b*C + ob + r))*HW + h*W + w] = acc[i][wt][r] + pbv[r];
        }
    }
}

extern "C" void kernel_launch(void* const* d_in, const int* in_sizes, int n_in,
                              void* d_out, int out_size, void* d_ws, size_t ws_size,
                              hipStream_t stream) {
    const float* x    = (const float*)d_in[0];
    const float* rw   = (const float*)d_in[1];
    const float* rb   = (const float*)d_in[2];
    const float* e0k  = (const float*)d_in[3];
    const float* e0g  = (const float*)d_in[4];
    const float* e0b  = (const float*)d_in[5];
    const float* e0m  = (const float*)d_in[6];
    const float* e0v  = (const float*)d_in[7];
    const float* e0pw = (const float*)d_in[8];
    const float* e0pb = (const float*)d_in[9];
    const float* e1k  = (const float*)d_in[10];
    const float* e1g  = (const float*)d_in[11];
    const float* e1b  = (const float*)d_in[12];
    const float* e1m  = (const float*)d_in[13];
    const float* e1v  = (const float*)d_in[14];
    const float* e1pw = (const float*)d_in[15];
    const float* e1pb = (const float*)d_in[16];
    const float* e2k  = (const float*)d_in[17];
    const float* e2g  = (const float*)d_in[18];
    const float* e2b  = (const float*)d_in[19];
    const float* e2m  = (const float*)d_in[20];
    const float* e2v  = (const float*)d_in[21];
    const float* e2pw = (const float*)d_in[22];
    const float* e2pb = (const float*)d_in[23];
    float* out = (float*)d_out;

    char* wsb = (char*)d_ws;
    float* pooled   = (float*)wsb;                       // 32768 B
    int*   idx      = (int*)(wsb + 32768);               // 128 B
    float* scAll    = (float*)(wsb + 32896);             // 3072 B
    float* shAll    = (float*)(wsb + 35968);             // 3072 B
    float* kf0      = (float*)(wsb + 39040);             // 12288 B
    float* kf1      = (float*)(wsb + 51328);             // 12288 B
    short* apackAll = (short*)(wsb + 63616);             // 786432 B (6 mats)

    pool_kernel<<<B*C, 256, 0, stream>>>(x, pooled);
    prep_kernel<<<194, 256, 0, stream>>>(e0pw, e1pw, e2pw, e2k, e0k, e1k,
                                         e0g, e0b, e0m, e0v,
                                         e1g, e1b, e1m, e1v,
                                         e2g, e2b, e2m, e2v,
                                         pooled, rw, rb, idx,
                                         apackAll, kf0, kf1, scAll, shAll);
    kconv<<<dim3(H, B), 256, 0, stream>>>(x, idx, kf0, kf1, shAll, apackAll,
                                          e0pb, e1pb, out);
    ke2<<<dim3(H, B), 256, 0, stream>>>(x, idx, scAll, shAll, apackAll,
                                        e2pb, out);
}

// Round 6
// 382.863 us; speedup vs baseline: 1.3387x; 1.0077x over previous
//
#include <hip/hip_runtime.h>
#include <math.h>

#define C 256
#define H 64
#define W 64
#define B 32
#define HW (H*W)
#define EPS 1e-5f
#define LSTR2 256  // shorts per row of the [w][ci] LDS tiles (512 B)

typedef __attribute__((ext_vector_type(8))) short short8;   // 8 bf16
typedef __attribute__((ext_vector_type(4))) short short4v;  // 4 bf16
typedef __attribute__((ext_vector_type(4))) float f32x4;

// Branchless gelu, exact-mode accurate: Abramowitz-Stegun 7.1.26 erf
// (max abs err 1.5e-7 -> gelu abs err <= ~1e-6, far under bf16 rounding).
__device__ __forceinline__ float gelu_fast(float z) {
    float a = fabsf(z) * 0.70710678f;
    float t = __frcp_rn(1.f + 0.3275911f * a);
    float p = t * (0.254829592f + t * (-0.284496736f + t * (1.421413741f +
              t * (-1.453152027f + t * 1.061405429f))));
    float e = __expf(-a * a);
    float q = 0.5f * fabsf(z) * p * e;
    return fmaxf(z, 0.f) - q;
}
__device__ __forceinline__ short f2bf(float f) {
    union { float f; unsigned u; } v; v.f = f;
    unsigned r = v.u + 0x7fffu + ((v.u >> 16) & 1u);
    return (short)(r >> 16);
}
__device__ __forceinline__ float bf2f(short s) {
    union { unsigned u; float f; } v; v.u = ((unsigned)(unsigned short)s) << 16;
    return v.f;
}
// XOR-swizzle (short-index units, 8-short groups) for the [w][ci] tiles.
__device__ __forceinline__ int swz8(int w) {
    return (((w & 7) ^ ((w >> 3) & 7)) << 3);
}
// XCD-aware (h,b) remap: each XCD gets 8-consecutive-h chunks (halo rows L2-hit),
// rotated across b so all XCDs get every batch (load-balanced vs expert routing).
__device__ __forceinline__ void swz_hb(int bx, int by, int& h, int& b) {
    int wg  = bx + (by << 6);
    int xcd = wg & 7, lin = wg >> 3;
    b = lin >> 3;
    int j = lin & 7;
    h = (((xcd + b) & 7) << 3) + j;
}

__global__ __launch_bounds__(256) void pool_kernel(const float* __restrict__ x,
                                                   float* __restrict__ pooled) {
    int bc = blockIdx.x;
    const float4* p4 = (const float4*)(x + (size_t)bc * HW);
    int t = threadIdx.x;
    float s = 0.f;
    for (int i = t; i < HW/4; i += 256) {
        float4 v = p4[i];
        s += v.x + v.y + v.z + v.w;
    }
    for (int off = 32; off > 0; off >>= 1) s += __shfl_down(s, off, 64);
    __shared__ float wsum[4];
    if ((t & 63) == 0) wsum[t >> 6] = s;
    __syncthreads();
    if (t == 0) pooled[bc] = (wsum[0]+wsum[1]+wsum[2]+wsum[3]) * (1.f/HW);
}

// blocks 0..191: pack 6 C*C fp32 matrices into bf16 MFMA fragments:
//   mat 0: pw0_hi  1: pw1_hi  2: pw2_hi  3: e2k_hi  4: pw2_lo  5: e2k_lo
// fragment chunk (kt,mt): lane holds M[o=mt*16+(lane&15)][ci=kt*32+(lane>>4)*8+j].
// block 192: fold BN into conv weights + sc/sh tables.
// block 193: routing (argmax logit; softmax/temp monotone, top-1 weight == 1).
__global__ __launch_bounds__(256) void prep_kernel(
    const float* __restrict__ s0, const float* __restrict__ s1,
    const float* __restrict__ s2, const float* __restrict__ s3,
    const float* __restrict__ e0k, const float* __restrict__ e1k,
    const float* __restrict__ g0, const float* __restrict__ b0,
    const float* __restrict__ m0, const float* __restrict__ v0,
    const float* __restrict__ g1, const float* __restrict__ b1,
    const float* __restrict__ m1, const float* __restrict__ v1,
    const float* __restrict__ g2, const float* __restrict__ b2,
    const float* __restrict__ m2, const float* __restrict__ v2,
    const float* __restrict__ pooled, const float* __restrict__ rw,
    const float* __restrict__ rb, int* __restrict__ idx,
    short* __restrict__ apackAll, float* __restrict__ kf0, float* __restrict__ kf1,
    float* __restrict__ scAll, float* __restrict__ shAll)
{
    if (blockIdx.x < 192) {
        int gid = blockIdx.x * 256 + threadIdx.x;       // 0..49151
        int mat = gid >> 13;                            // 0..5
        int c   = gid & 8191;
        int lane = c & 63;
        int ktmt = c >> 6;
        int mt = ktmt & 15, kt = ktmt >> 4;
        int o  = mt*16 + (lane & 15);
        int ci = kt*32 + (lane >> 4)*8;
        const float* src = (mat == 0) ? s0 : (mat == 1) ? s1 :
                           (mat == 2 || mat == 4) ? s2 : s3;
        bool lo = (mat >= 4);
        const float* p = src + o*C + ci;
        short8 v;
#pragma unroll
        for (int j = 0; j < 8; ++j) {
            float f = p[j];
            short hj = f2bf(f);
            v[j] = lo ? f2bf(f - bf2f(hj)) : hj;
        }
        *(short8*)&apackAll[(size_t)gid * 8] = v;
    } else if (blockIdx.x == 192) {
        int t = threadIdx.x;   // = ci
        {
            float s = g0[t] / sqrtf(v0[t] + EPS);
            scAll[t] = s; shAll[t] = b0[t] - m0[t]*s;
#pragma unroll
            for (int j = 0; j < 9; ++j) kf0[t*12+j] = e0k[t*9+j]*s;
            kf0[t*12+9] = 0.f; kf0[t*12+10] = 0.f; kf0[t*12+11] = 0.f;
        }
        {
            float s = g1[t] / sqrtf(v1[t] + EPS);
            scAll[C+t] = s; shAll[C+t] = b1[t] - m1[t]*s;
#pragma unroll
            for (int j = 0; j < 9; ++j) kf1[t*12+j] = e1k[t*9+j]*s;
            kf1[t*12+9] = 0.f; kf1[t*12+10] = 0.f; kf1[t*12+11] = 0.f;
        }
        {
            float s = g2[t] / sqrtf(v2[t] + EPS);
            scAll[2*C+t] = s; shAll[2*C+t] = b2[t] - m2[t]*s;
        }
    } else {
        // routing block — single UNIFORM barrier (no divergent __syncthreads)
        __shared__ float lg[3*B];
        int t = threadIdx.x;
        int e = t >> 6, lane = t & 63;
        if (e < 3) {
            for (int b = 0; b < B; ++b) {
                const float* p = pooled + b*C;
                const float* w = rw + e*C;
                float s = 0.f;
#pragma unroll
                for (int i = 0; i < 4; ++i) s += p[lane + i*64] * w[lane + i*64];
                for (int off = 32; off > 0; off >>= 1) s += __shfl_down(s, off, 64);
                if (lane == 0) lg[b*3 + e] = s + rb[e];
            }
        }
        __syncthreads();
        if (t < B) {
            float l0 = lg[t*3], l1 = lg[t*3+1], l2 = lg[t*3+2];
            int best = 0; float bv = l0;
            if (l1 > bv) { bv = l1; best = 1; }
            if (l2 > bv) { bv = l2; best = 2; }
            idx[t] = best;
        }
    }
}

// Register buffer for one conv iteration (all indices compile-time -> stays in VGPRs)
struct ConvBuf {
    float fr[3][16];
    float4 k0, k1;
    float shv;
};

// conv for dilation DIL; software-pipelined: iteration i+1's global loads are
// issued BEFORE iteration i's compute, so HBM/L2 latency hides under FMA+gelu.
// Writes gelu(BN(conv)) bf16 TRANSPOSED into lds[w][ci^swz].
// Numerically identical to the unpipelined version (same taps, same FMA order).
template<int DIL>
__device__ __forceinline__ void conv_rows_t(const float* __restrict__ x,
                                            const float* __restrict__ kf,
                                            const float* __restrict__ sh,
                                            short* __restrict__ lds,
                                            int b, int h, int t) {
    const int strip = t & 7;
    const int w0 = strip * 8;
    const int cib = t >> 3;
    const bool hasL = (strip > 0), hasR = (strip < 7);
    bool rv[3];
    int yy[3];
#pragma unroll
    for (int ky = 0; ky < 3; ++ky) {
        int y = h + (ky - 1) * DIL;
        rv[ky] = ((unsigned)y < H);      // wave-uniform
        yy[ky] = rv[ky] ? y : 0;         // safe row for predicated load
    }

    auto load = [&](ConvBuf& Bv, int iter) {
        int ci = iter*32 + cib;
        const float* xpl = x + (size_t)(b*C + ci) * HW;
#pragma unroll
        for (int ky = 0; ky < 3; ++ky) {
            const float* row = xpl + yy[ky]*W;
            float4 fa = (rv[ky] && hasL) ? *(const float4*)(row + w0 - 4) : float4{0,0,0,0};
            float4 fb = rv[ky] ? *(const float4*)(row + w0)     : float4{0,0,0,0};
            float4 fc = rv[ky] ? *(const float4*)(row + w0 + 4) : float4{0,0,0,0};
            float4 fd = (rv[ky] && hasR) ? *(const float4*)(row + w0 + 8) : float4{0,0,0,0};
            Bv.fr[ky][0]=fa.x;  Bv.fr[ky][1]=fa.y;  Bv.fr[ky][2]=fa.z;  Bv.fr[ky][3]=fa.w;
            Bv.fr[ky][4]=fb.x;  Bv.fr[ky][5]=fb.y;  Bv.fr[ky][6]=fb.z;  Bv.fr[ky][7]=fb.w;
            Bv.fr[ky][8]=fc.x;  Bv.fr[ky][9]=fc.y;  Bv.fr[ky][10]=fc.z; Bv.fr[ky][11]=fc.w;
            Bv.fr[ky][12]=fd.x; Bv.fr[ky][13]=fd.y; Bv.fr[ky][14]=fd.z; Bv.fr[ky][15]=fd.w;
        }
        Bv.k0 = *(const float4*)(kf + ci*12);
        Bv.k1 = *(const float4*)(kf + ci*12 + 4);
        Bv.shv = sh[ci];
    };
    auto comp = [&](ConvBuf& Bv, int iter) {
        int ci = iter*32 + cib;
        float wk[9] = {Bv.k0.x,Bv.k0.y,Bv.k0.z,Bv.k0.w,
                       Bv.k1.x,Bv.k1.y,Bv.k1.z,Bv.k1.w, kf[ci*12+8]};
        float acc8[8] = {0,0,0,0,0,0,0,0};
#pragma unroll
        for (int ky = 0; ky < 3; ++ky) {
            if (rv[ky]) {
#pragma unroll
                for (int kx = 0; kx < 3; ++kx) {
                    float wv = wk[ky*3+kx];
                    const int base = 4 + (kx - 1)*DIL;   // compile-time
#pragma unroll
                    for (int j = 0; j < 8; ++j) acc8[j] += wv * Bv.fr[ky][base + j];
                }
            }
        }
        float shv = Bv.shv;
#pragma unroll
        for (int j = 0; j < 8; ++j) {
            int w = w0 + j;
            lds[w*LSTR2 + (ci ^ swz8(w))] = f2bf(gelu_fast(acc8[j] + shv));
        }
    };

    ConvBuf A, Bb;
    load(A, 0);
#pragma unroll 1
    for (int it2 = 0; it2 < 4; ++it2) {
        load(Bb, it2*2 + 1);      // issue next loads, then compute current
        comp(A, it2*2);
        if (it2 < 3) load(A, it2*2 + 2);
        comp(Bb, it2*2 + 1);
    }
}

// Conv experts, fully fused per (h,b): dwconv+BN+gelu -> feat[w][ci] in LDS ->
// GEMM2 (pw_hi frags from global, feat B-frags via ds_read_b128) -> +pb -> out.
__global__ __launch_bounds__(256) void kconv(
    const float* __restrict__ x, const int* __restrict__ idx,
    const float* __restrict__ kf0, const float* __restrict__ kf1,
    const float* __restrict__ shAll, const short* __restrict__ apackAll,
    const float* __restrict__ e0pb, const float* __restrict__ e1pb,
    float* __restrict__ out)
{
    __shared__ short lds[W*LSTR2];   // 32 KB, [w][ci^swz]
    int h, b;
    swz_hb(blockIdx.x, blockIdx.y, h, b);
    const int e = idx[b];
    if (e >= 2) return;
    const int t = threadIdx.x;
    const int lane = t & 63, wid = t >> 6;
    const int l15 = lane & 15, quad = lane >> 4;

    if (e == 0) conv_rows_t<1>(x, kf0, shAll,     lds, b, h, t);
    else        conv_rows_t<2>(x, kf1, shAll + C, lds, b, h, t);
    __syncthreads();

    // GEMM2: D[o][w] = pw . feat ; wave wid owns o = wid*64..+63
    const short* pwf = apackAll + (size_t)e * 65536;
    f32x4 acc[4][4];
#pragma unroll
    for (int i = 0; i < 4; ++i)
#pragma unroll
        for (int wt = 0; wt < 4; ++wt) acc[i][wt] = (f32x4){0.f,0.f,0.f,0.f};
    for (int kt = 0; kt < 8; ++kt) {
        short8 bf[4];
#pragma unroll
        for (int wt = 0; wt < 4; ++wt) {
            int w = wt*16 + l15;
            bf[wt] = *(const short8*)&lds[w*LSTR2 + ((kt*32 + quad*8) ^ swz8(w))];
        }
        short8 af[4];
#pragma unroll
        for (int i = 0; i < 4; ++i)
            af[i] = *(const short8*)&pwf[((size_t)(kt*16 + wid*4 + i)*64 + lane)*8];
#pragma unroll
        for (int i = 0; i < 4; ++i)
#pragma unroll
            for (int wt = 0; wt < 4; ++wt)
                acc[i][wt] = __builtin_amdgcn_mfma_f32_16x16x32_bf16(
                    af[i], bf[wt], acc[i][wt], 0, 0, 0);
    }

    const float* pb = (e == 0) ? e0pb : e1pb;
#pragma unroll
    for (int i = 0; i < 4; ++i) {
        int ob = wid*64 + i*16 + quad*4;
        float4 p4 = *(const float4*)&pb[ob];
        float pbv[4] = {p4.x, p4.y, p4.z, p4.w};
#pragma unroll
        for (int wt = 0; wt < 4; ++wt) {
            int w = wt*16 + l15;
#pragma unroll
            for (int r = 0; r < 4; ++r)
                out[((size_t)(b*C + ob + r))*HW + h*W + w] = acc[i][wt][r] + pbv[r];
        }
    }
}

// 3-product split-bf16 GEMM over [w][ci] hi/lo LDS tiles (ds_read_b128 B-frags):
// acc += Ahi*Bhi + Ahi*Blo + Alo*Bhi  (~fp32 accurate; lo*lo term ~2^-18 dropped)
__device__ __forceinline__ void gemm3t(const short* __restrict__ aH,
                                       const short* __restrict__ aL,
                                       const short* __restrict__ ldsH,
                                       const short* __restrict__ ldsL,
                                       int lane, int wid, f32x4 acc[4][4])
{
    const int l15 = lane & 15, quad = lane >> 4;
    for (int kt = 0; kt < 8; ++kt) {
        short8 bH[4], bL[4];
#pragma unroll
        for (int wt = 0; wt < 4; ++wt) {
            int w = wt*16 + l15;
            int off = w*LSTR2 + ((kt*32 + quad*8) ^ swz8(w));
            bH[wt] = *(const short8*)&ldsH[off];
            bL[wt] = *(const short8*)&ldsL[off];
        }
        short8 fH[4], fL[4];
#pragma unroll
        for (int i = 0; i < 4; ++i) {
            size_t off = ((size_t)(kt*16 + wid*4 + i)*64 + lane)*8;
            fH[i] = *(const short8*)&aH[off];
            fL[i] = *(const short8*)&aL[off];
        }
#pragma unroll
        for (int i = 0; i < 4; ++i)
#pragma unroll
            for (int wt = 0; wt < 4; ++wt) {
                acc[i][wt] = __builtin_amdgcn_mfma_f32_16x16x32_bf16(fH[i], bH[wt], acc[i][wt], 0, 0, 0);
                acc[i][wt] = __builtin_amdgcn_mfma_f32_16x16x32_bf16(fH[i], bL[wt], acc[i][wt], 0, 0, 0);
                acc[i][wt] = __builtin_amdgcn_mfma_f32_16x16x32_bf16(fL[i], bH[wt], acc[i][wt], 0, 0, 0);
            }
    }
}

// e2 expert, fused full path per (h,b): x hi/lo [w][ci] tiles -> e2k GEMM (3-prod)
// -> BN+gelu -> feat hi/lo tiles -> pw2 GEMM (3-prod) -> +pb -> out (fp32).
__global__ __launch_bounds__(256) void ke2(
    const float* __restrict__ x, const int* __restrict__ idx,
    const float* __restrict__ scAll, const float* __restrict__ shAll,
    const short* __restrict__ apackAll, const float* __restrict__ e2pb,
    float* __restrict__ out)
{
    __shared__ short ldsH[W*LSTR2];   // 32 KB hi tile [w][ci^swz]
    __shared__ short ldsL[W*LSTR2];   // 32 KB lo tile
    int h, b;
    swz_hb(blockIdx.x, blockIdx.y, h, b);
    if (idx[b] != 2) return;
    const int t = threadIdx.x;
    const int lane = t & 63, wid = t >> 6;
    const int l15 = lane & 15, quad = lane >> 4;

    // stage x row h: channel-direction loads (lane = w -> 256B/inst coalesced),
    // 16B LDS row writes
    {
        const int w = t & 63;
        const int vsw = swz8(w);
        const int ci0w = wid * 64;
#pragma unroll 1
        for (int k = 0; k < 8; ++k) {
            int ci0 = ci0w + k*8;
            const float* px = x + ((size_t)(b*C + ci0)*H + h)*W + w;
            float f[8];
#pragma unroll
            for (int j = 0; j < 8; ++j) f[j] = px[(size_t)j * HW];
            short8 hi, lo;
#pragma unroll
            for (int j = 0; j < 8; ++j) {
                short hj = f2bf(f[j]);
                hi[j] = hj;
                lo[j] = f2bf(f[j] - bf2f(hj));
            }
            int col = ci0 ^ vsw;
            *(short8*)&ldsH[w*LSTR2 + col] = hi;
            *(short8*)&ldsL[w*LSTR2 + col] = lo;
        }
    }
    __syncthreads();

    // GEMM1: z[co][w] = e2k @ x  (split-accurate)
    f32x4 acc[4][4];
#pragma unroll
    for (int i = 0; i < 4; ++i)
#pragma unroll
        for (int wt = 0; wt < 4; ++wt) acc[i][wt] = (f32x4){0.f,0.f,0.f,0.f};
    gemm3t(apackAll + (size_t)3*65536, apackAll + (size_t)5*65536,
           ldsH, ldsL, lane, wid, acc);
    __syncthreads();   // all waves done reading x before feat overwrites tiles

    // BN + gelu; split feat hi/lo, store [w][co^swz]
    {
        const float* sc2 = scAll + 2*C;
        const float* sh2 = shAll + 2*C;
#pragma unroll
        for (int i = 0; i < 4; ++i) {
            int cob = wid*64 + i*16 + quad*4;
            float4 s4 = *(const float4*)&sc2[cob];
            float4 h4 = *(const float4*)&sh2[cob];
            float ss[4] = {s4.x, s4.y, s4.z, s4.w};
            float hh[4] = {h4.x, h4.y, h4.z, h4.w};
#pragma unroll
            for (int wt = 0; wt < 4; ++wt) {
                int w = wt*16 + l15;
                int col = cob ^ swz8(w);   // swz flips bits>=3: 4-short groups kept
                short4v ph, pl;
#pragma unroll
                for (int r = 0; r < 4; ++r) {
                    float f = gelu_fast(acc[i][wt][r]*ss[r] + hh[r]);
                    short hj = f2bf(f);
                    ph[r] = hj;
                    pl[r] = f2bf(f - bf2f(hj));
                }
                *(short4v*)&ldsH[w*LSTR2 + col] = ph;
                *(short4v*)&ldsL[w*LSTR2 + col] = pl;
            }
        }
    }
    __syncthreads();

    // GEMM2: out[o][w] = pw2 @ feat  (split-accurate)
#pragma unroll
    for (int i = 0; i < 4; ++i)
#pragma unroll
        for (int wt = 0; wt < 4; ++wt) acc[i][wt] = (f32x4){0.f,0.f,0.f,0.f};
    gemm3t(apackAll + (size_t)2*65536, apackAll + (size_t)4*65536,
           ldsH, ldsL, lane, wid, acc);

    // epilogue: + pb, store fp32
#pragma unroll
    for (int i = 0; i < 4; ++i) {
        int ob = wid*64 + i*16 + quad*4;
        float4 p4 = *(const float4*)&e2pb[ob];
        float pbv[4] = {p4.x, p4.y, p4.z, p4.w};
#pragma unroll
        for (int wt = 0; wt < 4; ++wt) {
            int w = wt*16 + l15;
#pragma unroll
            for (int r = 0; r < 4; ++r)
                out[((size_t)(b*C + ob + r))*HW + h*W + w] = acc[i][wt][r] + pbv[r];
        }
    }
}

extern "C" void kernel_launch(void* const* d_in, const int* in_sizes, int n_in,
                              void* d_out, int out_size, void* d_ws, size_t ws_size,
                              hipStream_t stream) {
    const float* x    = (const float*)d_in[0];
    const float* rw   = (const float*)d_in[1];
    const float* rb   = (const float*)d_in[2];
    const float* e0k  = (const float*)d_in[3];
    const float* e0g  = (const float*)d_in[4];
    const float* e0b  = (const float*)d_in[5];
    const float* e0m  = (const float*)d_in[6];
    const float* e0v  = (const float*)d_in[7];
    const float* e0pw = (const float*)d_in[8];
    const float* e0pb = (const float*)d_in[9];
    const float* e1k  = (const float*)d_in[10];
    const float* e1g  = (const float*)d_in[11];
    const float* e1b  = (const float*)d_in[12];
    const float* e1m  = (const float*)d_in[13];
    const float* e1v  = (const float*)d_in[14];
    const float* e1pw = (const float*)d_in[15];
    const float* e1pb = (const float*)d_in[16];
    const float* e2k  = (const float*)d_in[17];
    const float* e2g  = (const float*)d_in[18];
    const float* e2b  = (const float*)d_in[19];
    const float* e2m  = (const float*)d_in[20];
    const float* e2v  = (const float*)d_in[21];
    const float* e2pw = (const float*)d_in[22];
    const float* e2pb = (const float*)d_in[23];
    float* out = (float*)d_out;

    char* wsb = (char*)d_ws;
    float* pooled   = (float*)wsb;                       // 32768 B
    int*   idx      = (int*)(wsb + 32768);               // 128 B
    float* scAll    = (float*)(wsb + 32896);             // 3072 B
    float* shAll    = (float*)(wsb + 35968);             // 3072 B
    float* kf0      = (float*)(wsb + 39040);             // 12288 B
    float* kf1      = (float*)(wsb + 51328);             // 12288 B
    short* apackAll = (short*)(wsb + 63616);             // 786432 B (6 mats)

    pool_kernel<<<B*C, 256, 0, stream>>>(x, pooled);
    prep_kernel<<<194, 256, 0, stream>>>(e0pw, e1pw, e2pw, e2k, e0k, e1k,
                                         e0g, e0b, e0m, e0v,
                                         e1g, e1b, e1m, e1v,
                                         e2g, e2b, e2m, e2v,
                                         pooled, rw, rb, idx,
                                         apackAll, kf0, kf1, scAll, shAll);
    kconv<<<dim3(H, B), 256, 0, stream>>>(x, idx, kf0, kf1, shAll, apackAll,
                                          e0pb, e1pb, out);
    ke2<<<dim3(H, B), 256, 0, stream>>>(x, idx, scAll, shAll, apackAll,
                                        e2pb, out);
}